// Round 11
// baseline (751.333 us; speedup 1.0000x reference)
//
#include <hip/hip_runtime.h>
#include <hip/hip_bf16.h>
#include <cmath>

#define BB 16
#define TT 8192
#define MM (BB*TT)
#define FF 256
#define TBF 5.0f
#define PROJN 29

typedef __attribute__((ext_vector_type(8))) short short8;
typedef __attribute__((ext_vector_type(4))) float f32x4;

// tanh-form gelu: x*sigmoid(x*(c1 + c2*x^2)); max abs err vs exact ~3e-4.
__device__ __forceinline__ float gelu_fast(float x){
    const float x2 = x*x;
    const float v  = x*fmaf(0.07135481627f, x2, 1.595769122f);
    const float e  = __expf(-v);
    return x*__builtin_amdgcn_rcpf(1.0f + e);
}
__device__ __forceinline__ float softplusf_(float v){
    return fmaxf(v,0.0f) + log1pf(__expf(-fabsf(v)));
}
__device__ __forceinline__ unsigned pack2bf(float a, float b){
    __hip_bfloat16 ha = __float2bfloat16(a);
    __hip_bfloat16 hb = __float2bfloat16(b);
    const unsigned ua = *reinterpret_cast<const unsigned short*>(&ha);
    const unsigned ub = *reinterpret_cast<const unsigned short*>(&hb);
    return ua | (ub<<16);
}
__device__ __forceinline__ float bf2f(unsigned short u){
    unsigned v = ((unsigned)u)<<16;
    return *reinterpret_cast<float*>(&v);
}
__device__ __forceinline__ float4 unpack4(uint2 q){
    float4 f;
    f.x = bf2f((unsigned short)(q.x&0xffff)); f.y = bf2f((unsigned short)(q.x>>16));
    f.z = bf2f((unsigned short)(q.y&0xffff)); f.w = bf2f((unsigned short)(q.y>>16));
    return f;
}

// Layer images: wimg[layer][kc][n][40] bf16, [n][kp] = w11[kc*32+kp][n] (kp<32; pad 0).
// Proj image (blocks 24..31): wpimg[kc][n 0..31][40].
__global__ __launch_bounds__(256) void wprep_kernel(
    const float* __restrict__ w11, const float* __restrict__ wproj,
    __hip_bfloat16* __restrict__ wimg, __hip_bfloat16* __restrict__ wpimg)
{
    if(blockIdx.x < 24){
        const int layer = blockIdx.x>>3, kc = blockIdx.x&7;
        const float* __restrict__ w = w11 + (size_t)layer*FF*FF;
        __hip_bfloat16* __restrict__ o = wimg + (size_t)layer*81920 + kc*10240;
        for(int i=threadIdx.x; i<10240; i+=256){
            const int n = i/40, kp = i - n*40;
            const float v = (kp<32) ? w[(size_t)(kc*32+kp)*FF + n] : 0.0f;
            o[i] = __float2bfloat16(v);
        }
    } else {
        const int kc = blockIdx.x - 24;
        __hip_bfloat16* __restrict__ o = wpimg + (size_t)kc*1280;
        for(int i=threadIdx.x; i<1280; i+=256){
            const int n = i/40, kp = i - n*40;
            const float v = (kp<32 && n<PROJN) ? wproj[(size_t)(kc*32+kp)*PROJN + n] : 0.0f;
            o[i] = __float2bfloat16(v);
        }
    }
}

// One layer: 32 rows x 256 cols per block, 256 threads = 4 waves.
// Wave owns 32 rows x 64 cols (acc 2x4). No hstash: residual re-read from
// L2-hot hbin (PRE=0) or recomputed rank-1 (PRE=1). LDS ~18KB -> 8 blocks/CU.
template<int PRE>
__global__ __launch_bounds__(256,8) void layer_kernel(
    const __hip_bfloat16* __restrict__ hbin, __hip_bfloat16* __restrict__ hbout,
    const float* __restrict__ xsrc,
    const float* __restrict__ w_pre, const float* __restrict__ b_pre,
    const float* __restrict__ mask,
    const float* __restrict__ dwk, const float* __restrict__ dwb,
    const float* __restrict__ g1, const float* __restrict__ b1,
    const __hip_bfloat16* __restrict__ wimgL, const float* __restrict__ b11,
    const float* __restrict__ g2, const float* __restrict__ b2,
    const int dil)
{
    __shared__ __hip_bfloat16 ytile[32][260];   // stride 260: conflict-free
    __shared__ float redS[32][4];
    __shared__ float redQ[32][4];
    __shared__ float stat[32][2];

    const int tid  = threadIdx.x;
    const int wave = tid>>6, lane = tid&63;
    const int l15  = lane&15, qq = lane>>4;

    int bid = blockIdx.x;                        // XCD swizzle (4096%8==0)
    bid = (bid&7)*((int)gridDim.x>>3) + (bid>>3);
    const int m0 = bid*32;
    const int b  = m0/TT;
    const int t0 = m0 - b*TT;
    const float* __restrict__ mrow = mask + (size_t)b*TT;

    // ---- Phase 1: conv + LN1 + gelu -> ytile. 8 rows/wave.
    const int f0 = lane*4;
    const float4 k0 = *(const float4*)&dwk[f0];
    const float4 k1 = *(const float4*)&dwk[FF+f0];
    const float4 k2 = *(const float4*)&dwk[2*FF+f0];
    const float4 cb = *(const float4*)&dwb[f0];
    const float4 g1v= *(const float4*)&g1[f0];
    const float4 b1v= *(const float4*)&b1[f0];
    float4 wp4, bp4;
    if(PRE){ wp4 = *(const float4*)&w_pre[f0]; bp4 = *(const float4*)&b_pre[f0]; }

    #pragma unroll 4
    for(int rr=0; rr<8; ++rr){
        const int r = wave*8+rr;
        const int m = m0+r, t = t0+r;
        const int okl = (t>=dil)   ? 1 : 0;
        const int okr = (t+dil<TT) ? 1 : 0;
        const int ml  = m - dil*okl;
        const int mr  = m + dil*okr;
        const float mkc = mrow[t];
        const float mkl = mrow[t - dil*okl] * (float)okl;
        const float mkr = mrow[t + dil*okr] * (float)okr;
        float4 hc, hl, hr;
        if(PRE){
            const float xc_ = xsrc[(size_t)m *2];
            const float xl_ = xsrc[(size_t)ml*2];
            const float xr_ = xsrc[(size_t)mr*2];
            hc.x=fmaf(xc_,wp4.x,bp4.x); hc.y=fmaf(xc_,wp4.y,bp4.y);
            hc.z=fmaf(xc_,wp4.z,bp4.z); hc.w=fmaf(xc_,wp4.w,bp4.w);
            hl.x=fmaf(xl_,wp4.x,bp4.x); hl.y=fmaf(xl_,wp4.y,bp4.y);
            hl.z=fmaf(xl_,wp4.z,bp4.z); hl.w=fmaf(xl_,wp4.w,bp4.w);
            hr.x=fmaf(xr_,wp4.x,bp4.x); hr.y=fmaf(xr_,wp4.y,bp4.y);
            hr.z=fmaf(xr_,wp4.z,bp4.z); hr.w=fmaf(xr_,wp4.w,bp4.w);
        } else {
            hc = unpack4(*(const uint2*)&hbin[(size_t)m *FF + f0]);
            hl = unpack4(*(const uint2*)&hbin[(size_t)ml*FF + f0]);
            hr = unpack4(*(const uint2*)&hbin[(size_t)mr*FF + f0]);
        }
        float4 a;
        a.x = fmaf(hc.x*mkc, k1.x, cb.x);
        a.y = fmaf(hc.y*mkc, k1.y, cb.y);
        a.z = fmaf(hc.z*mkc, k1.z, cb.z);
        a.w = fmaf(hc.w*mkc, k1.w, cb.w);
        a.x = fmaf(hl.x*mkl, k0.x, a.x);
        a.y = fmaf(hl.y*mkl, k0.y, a.y);
        a.z = fmaf(hl.z*mkl, k0.z, a.z);
        a.w = fmaf(hl.w*mkl, k0.w, a.w);
        a.x = fmaf(hr.x*mkr, k2.x, a.x);
        a.y = fmaf(hr.y*mkr, k2.y, a.y);
        a.z = fmaf(hr.z*mkr, k2.z, a.z);
        a.w = fmaf(hr.w*mkr, k2.w, a.w);
        float s  = a.x+a.y+a.z+a.w;
        float sq = fmaf(a.x,a.x, fmaf(a.y,a.y, fmaf(a.z,a.z, a.w*a.w)));
        #pragma unroll
        for(int o=32;o>0;o>>=1){
            s  += __shfl_xor(s,o,64);
            sq += __shfl_xor(sq,o,64);
        }
        const float mean = s*(1.0f/FF);
        const float var  = fmaf(-mean, mean, sq*(1.0f/FF));
        const float rs = rsqrtf(var + 1e-5f);
        const float y0 = gelu_fast(fmaf((a.x-mean)*rs, g1v.x, b1v.x));
        const float y1 = gelu_fast(fmaf((a.y-mean)*rs, g1v.y, b1v.y));
        const float y2 = gelu_fast(fmaf((a.z-mean)*rs, g1v.z, b1v.z));
        const float y3 = gelu_fast(fmaf((a.w-mean)*rs, g1v.w, b1v.w));
        *(uint2*)&ytile[r][f0] = make_uint2(pack2bf(y0,y1), pack2bf(y2,y3));
    }

    __syncthreads();

    // ---- Phase 2: MFMA GEMM. Wave owns 32 rows x cols [wave*64, wave*64+64).
    const int wc = wave*64;
    f32x4 acc[2][4];
    #pragma unroll
    for(int mf=0;mf<2;++mf)
        #pragma unroll
        for(int nf=0;nf<4;++nf)
            acc[mf][nf] = (f32x4){0.f,0.f,0.f,0.f};

    #pragma unroll
    for(int kc=0;kc<8;++kc){
        short8 bfv[4];
        #pragma unroll
        for(int nf=0;nf<4;++nf)
            bfv[nf] = *(const short8*)&wimgL[(size_t)kc*10240 + (wc+nf*16+l15)*40 + qq*8];
        short8 af[2];
        #pragma unroll
        for(int mf=0;mf<2;++mf)
            af[mf] = *(const short8*)&ytile[mf*16+l15][kc*32 + qq*8];
        #pragma unroll
        for(int nf=0;nf<4;++nf)
            #pragma unroll
            for(int mf=0;mf<2;++mf)
                acc[mf][nf] = __builtin_amdgcn_mfma_f32_16x16x32_bf16(af[mf], bfv[nf], acc[mf][nf], 0,0,0);
    }

    // ---- Phase 3: +b11, LN2 (cross-wave), gelu, residual, store bf16.
    float b11c[4], g2c[4], b2c[4], wpc[4], bpc[4];
    #pragma unroll
    for(int nf=0;nf<4;++nf){
        const int col = wc + nf*16 + l15;
        b11c[nf]=b11[col]; g2c[nf]=g2[col]; b2c[nf]=b2[col];
        if(PRE){ wpc[nf]=w_pre[col]; bpc[nf]=b_pre[col]; }
    }
    #pragma unroll
    for(int mf=0;mf<2;++mf){
        #pragma unroll
        for(int rg=0;rg<4;++rg){
            float s=0.f, sq=0.f;
            #pragma unroll
            for(int nf=0;nf<4;++nf){
                const float v = acc[mf][nf][rg] + b11c[nf];
                s += v; sq = fmaf(v,v,sq);
            }
            #pragma unroll
            for(int o=1;o<16;o<<=1){ s += __shfl_xor(s,o,64); sq += __shfl_xor(sq,o,64); }
            if(l15==0){
                const int row = mf*16 + qq*4 + rg;
                redS[row][wave]=s; redQ[row][wave]=sq;
            }
        }
    }
    __syncthreads();
    if(tid < 32){
        const float s  = redS[tid][0]+redS[tid][1]+redS[tid][2]+redS[tid][3];
        const float q2 = redQ[tid][0]+redQ[tid][1]+redQ[tid][2]+redQ[tid][3];
        const float mean = s*(1.0f/FF);
        const float var  = fmaf(-mean, mean, q2*(1.0f/FF));
        stat[tid][0]=mean; stat[tid][1]=rsqrtf(var+1e-5f);
    }
    __syncthreads();
    #pragma unroll
    for(int mf=0;mf<2;++mf){
        #pragma unroll
        for(int rg=0;rg<4;++rg){
            const int row = mf*16 + qq*4 + rg;
            const float mean = stat[row][0], rs = stat[row][1];
            const size_t gbase = (size_t)(m0+row)*FF;
            float x0r;
            if(PRE) x0r = xsrc[(size_t)(m0+row)*2];
            #pragma unroll
            for(int nf=0;nf<4;++nf){
                const int col = wc + nf*16 + l15;
                const float v  = acc[mf][nf][rg] + b11c[nf];
                const float yn = fmaf((v-mean)*rs, g2c[nf], b2c[nf]);
                float res;
                if(PRE) res = fmaf(x0r, wpc[nf], bpc[nf]);
                else    res = bf2f(*reinterpret_cast<const unsigned short*>(&hbin[gbase+col]));
                hbout[gbase+col] = __float2bfloat16(res + gelu_fast(yn));
            }
        }
    }
}

// ---------- Fused proj + spline: 128 rows/block (1024 blocks -> 4/CU) ----------
__global__ __launch_bounds__(256,4) void projspline_kernel(
    const __hip_bfloat16* __restrict__ hbin, const float* __restrict__ mask,
    const __hip_bfloat16* __restrict__ wpimg, const float* __restrict__ bproj,
    const float* __restrict__ x, float* __restrict__ out,
    float* __restrict__ logdet)
{
    __shared__ __hip_bfloat16 ytile[32][260];
    __shared__ float Pl[128][33];
    __shared__ float red[256];

    const int tid = threadIdx.x;
    const int wave = tid>>6, lane = tid&63;
    const int l15 = lane&15, qq = lane>>4;
    const int m0 = blockIdx.x*128;
    const int f0 = lane*4;

    const int rh  = (wave&1)*16;          // row half within 32-row chunk
    const int wc2 = (wave>>1)*16;         // col group (0 or 16)
    const int col = wc2 + l15;            // 0..31
    const float bp = (col<PROJN)? bproj[col] : 0.0f;

    for(int chk=0; chk<4; ++chk){
        const int mc = m0 + chk*32;
        #pragma unroll
        for(int rr=0; rr<8; ++rr){
            const int r = wave*8+rr;
            const int m = mc+r;
            const float mk = mask[m];
            const float4 hc = unpack4(*(const uint2*)&hbin[(size_t)m*FF + f0]);
            *(uint2*)&ytile[r][f0] = make_uint2(pack2bf(hc.x*mk, hc.y*mk), pack2bf(hc.z*mk, hc.w*mk));
        }
        __syncthreads();

        f32x4 acc = (f32x4){0.f,0.f,0.f,0.f};
        #pragma unroll
        for(int kc=0;kc<8;++kc){
            const short8 bfv = *(const short8*)&wpimg[(size_t)kc*1280 + (wc2+l15)*40 + qq*8];
            const short8 af  = *(const short8*)&ytile[rh+l15][kc*32 + qq*8];
            acc = __builtin_amdgcn_mfma_f32_16x16x32_bf16(af, bfv, acc, 0,0,0);
        }
        #pragma unroll
        for(int rg=0;rg<4;++rg){
            const int row = rh + qq*4 + rg;
            const float mk = mask[mc+row];
            Pl[chk*32+row][col] = (acc[rg] + bp)*mk;
        }
        __syncthreads();
    }

    // ---- spline: rows 0..127 on threads 0..127
    float lv_mk = 0.0f;
    if(tid < 128){
        const int m = m0 + tid;
        float p[29];
        #pragma unroll
        for(int j=0;j<29;++j) p[j] = Pl[tid][j];
        const float x0 = x[(size_t)m*2];
        const float x1 = x[(size_t)m*2+1];
        const float mk = mask[m];
        const float sc = 0.0625f;

        float cw[11], ch_[11], d[11];
        {
            float mx=-1e30f;
            #pragma unroll
            for(int j=0;j<10;++j) mx = fmaxf(mx, p[j]);
            float e[10]; float se=0.f;
            #pragma unroll
            for(int j=0;j<10;++j){ e[j]=__expf((p[j]-mx)*sc); se+=e[j]; }
            const float inv = __builtin_amdgcn_rcpf(se);
            float cum=0.f;
            cw[0]=-TBF;
            #pragma unroll
            for(int j=0;j<10;++j){ cum += fmaf(0.99f, e[j]*inv, 0.001f); cw[j+1]=fmaf(2.0f*TBF,cum,-TBF); }
            cw[10]=TBF;
        }
        {
            float mx=-1e30f;
            #pragma unroll
            for(int j=0;j<10;++j) mx = fmaxf(mx, p[10+j]);
            float e[10]; float se=0.f;
            #pragma unroll
            for(int j=0;j<10;++j){ e[j]=__expf((p[10+j]-mx)*sc); se+=e[j]; }
            const float inv = __builtin_amdgcn_rcpf(se);
            float cum=0.f;
            ch_[0]=-TBF;
            #pragma unroll
            for(int j=0;j<10;++j){ cum += fmaf(0.99f, e[j]*inv, 0.001f); ch_[j+1]=fmaf(2.0f*TBF,cum,-TBF); }
            ch_[10]=TBF;
        }
        d[0]=1.0f; d[10]=1.0f;
        #pragma unroll
        for(int k=1;k<10;++k) d[k] = 0.001f + softplusf_(p[19+k]);

        const bool inside = (x1>=-TBF)&&(x1<=TBF);
        const float xc = fminf(fmaxf(x1,-TBF),TBF);

        float icw=cw[0], ibw=cw[1]-cw[0], ich=ch_[0], ibh=ch_[1]-ch_[0], dk=d[0], dk1=d[1];
        #pragma unroll
        for(int j=1;j<10;++j){
            const bool sel = (xc>=cw[j]);
            icw = sel? cw[j]        : icw;
            ibw = sel? cw[j+1]-cw[j]: ibw;
            ich = sel? ch_[j]       : ich;
            ibh = sel? ch_[j+1]-ch_[j]: ibh;
            dk  = sel? d[j]         : dk;
            dk1 = sel? d[j+1]       : dk1;
        }

        const float delta = __fdividef(ibh, ibw);
        const float th = __fdividef(xc-icw, ibw);
        const float th1m = th*(1.0f-th);
        const float denom = fmaf(fmaf(-2.0f,delta,dk+dk1), th1m, delta);
        const float num = ibh*fmaf(delta*th, th, dk*th1m);
        const float rcd = __builtin_amdgcn_rcpf(denom);
        const float yv = ich + num*rcd;
        const float omt = 1.0f-th;
        const float dnum = delta*delta*(dk1*th*th + 2.0f*delta*th1m + dk*omt*omt);
        const float lad = __logf(dnum*rcd*rcd);
        const float y1 = inside? yv : x1;
        const float lv = inside? lad : 0.0f;

        out[(size_t)m*2]   = x0*mk;
        out[(size_t)m*2+1] = y1*mk;
        lv_mk = lv*mk;
    }

    red[tid] = lv_mk;
    __syncthreads();
    #pragma unroll
    for(int s=128;s>0;s>>=1){ if(tid<s) red[tid]+=red[tid+s]; __syncthreads(); }
    if(tid==0) atomicAdd(&logdet[blockIdx.x>>6], red[0]);   // 64 blocks / batch
}

// ---------- Fallback pair (used only if ws can't host wimg) ----------
__global__ __launch_bounds__(256,4) void proj_kernel(
    const __hip_bfloat16* __restrict__ hbin, const float* __restrict__ mask,
    const __hip_bfloat16* __restrict__ wpimg, const float* __restrict__ bproj,
    float* __restrict__ P)
{
    __shared__ __hip_bfloat16 ytile[64][260];
    const int tid = threadIdx.x;
    const int wave = tid>>6, lane = tid&63;
    const int l15 = lane&15, qq = lane>>4;
    const int m0 = blockIdx.x*64;
    const int f0 = lane*4;

    #pragma unroll 4
    for(int rr=0; rr<16; ++rr){
        const int r = wave*16+rr;
        const int m = m0+r;
        const float mk = mask[m];
        const float4 hc = unpack4(*(const uint2*)&hbin[(size_t)m*FF + f0]);
        *(uint2*)&ytile[r][f0] = make_uint2(pack2bf(hc.x*mk, hc.y*mk), pack2bf(hc.z*mk, hc.w*mk));
    }
    __syncthreads();

    const int rh = (wave&1)*32, wc2 = (wave>>1)*16;
    f32x4 acc[2];
    acc[0] = (f32x4){0.f,0.f,0.f,0.f};
    acc[1] = (f32x4){0.f,0.f,0.f,0.f};
    #pragma unroll
    for(int kc=0;kc<8;++kc){
        const short8 bfv = *(const short8*)&wpimg[(size_t)kc*1280 + (wc2+l15)*40 + qq*8];
        #pragma unroll
        for(int mf=0;mf<2;++mf){
            const short8 af = *(const short8*)&ytile[rh+mf*16+l15][kc*32 + qq*8];
            acc[mf] = __builtin_amdgcn_mfma_f32_16x16x32_bf16(af, bfv, acc[mf], 0,0,0);
        }
    }
    const int col = wc2 + l15;
    const float bp = (col<PROJN)? bproj[col] : 0.0f;
    #pragma unroll
    for(int mf=0;mf<2;++mf){
        #pragma unroll
        for(int rg=0;rg<4;++rg){
            const int row = rh + mf*16 + qq*4 + rg;
            const float mk = mask[m0+row];
            P[(size_t)(m0+row)*32 + col] = (acc[mf][rg] + bp)*mk;
        }
    }
}

__global__ __launch_bounds__(256) void spline_kernel(
    const float* __restrict__ P, const float* __restrict__ x,
    const float* __restrict__ mask, float* __restrict__ out,
    float* __restrict__ logdet)
{
    const int tid = threadIdx.x;
    const int m = blockIdx.x*256 + tid;
    float p[32];
    #pragma unroll
    for(int j=0;j<8;++j) ((float4*)p)[j] = ((const float4*)P)[(size_t)m*8+j];
    const float x0 = x[(size_t)m*2];
    const float x1 = x[(size_t)m*2+1];
    const float mk = mask[m];
    const float sc = 0.0625f;

    float cw[11], ch_[11], d[11];
    {
        float mx=-1e30f;
        #pragma unroll
        for(int j=0;j<10;++j) mx = fmaxf(mx, p[j]);
        float e[10]; float se=0.f;
        #pragma unroll
        for(int j=0;j<10;++j){ e[j]=__expf((p[j]-mx)*sc); se+=e[j]; }
        const float inv = __builtin_amdgcn_rcpf(se);
        float cum=0.f;
        cw[0]=-TBF;
        #pragma unroll
        for(int j=0;j<10;++j){ cum += fmaf(0.99f, e[j]*inv, 0.001f); cw[j+1]=fmaf(2.0f*TBF,cum,-TBF); }
        cw[10]=TBF;
    }
    {
        float mx=-1e30f;
        #pragma unroll
        for(int j=0;j<10;++j) mx = fmaxf(mx, p[10+j]);
        float e[10]; float se=0.f;
        #pragma unroll
        for(int j=0;j<10;++j){ e[j]=__expf((p[10+j]-mx)*sc); se+=e[j]; }
        const float inv = __builtin_amdgcn_rcpf(se);
        float cum=0.f;
        ch_[0]=-TBF;
        #pragma unroll
        for(int j=0;j<10;++j){ cum += fmaf(0.99f, e[j]*inv, 0.001f); ch_[j+1]=fmaf(2.0f*TBF,cum,-TBF); }
        ch_[10]=TBF;
    }
    d[0]=1.0f; d[10]=1.0f;
    #pragma unroll
    for(int k=1;k<10;++k) d[k] = 0.001f + softplusf_(p[19+k]);

    const bool inside = (x1>=-TBF)&&(x1<=TBF);
    const float xc = fminf(fmaxf(x1,-TBF),TBF);

    float icw=cw[0], ibw=cw[1]-cw[0], ich=ch_[0], ibh=ch_[1]-ch_[0], dk=d[0], dk1=d[1];
    #pragma unroll
    for(int j=1;j<10;++j){
        const bool sel = (xc>=cw[j]);
        icw = sel? cw[j]        : icw;
        ibw = sel? cw[j+1]-cw[j]: ibw;
        ich = sel? ch_[j]       : ich;
        ibh = sel? ch_[j+1]-ch_[j]: ibh;
        dk  = sel? d[j]         : dk;
        dk1 = sel? d[j+1]       : dk1;
    }

    const float delta = __fdividef(ibh, ibw);
    const float th = __fdividef(xc-icw, ibw);
    const float th1m = th*(1.0f-th);
    const float denom = fmaf(fmaf(-2.0f,delta,dk+dk1), th1m, delta);
    const float num = ibh*fmaf(delta*th, th, dk*th1m);
    const float rcd = __builtin_amdgcn_rcpf(denom);
    const float yv = ich + num*rcd;
    const float omt = 1.0f-th;
    const float dnum = delta*delta*(dk1*th*th + 2.0f*delta*th1m + dk*omt*omt);
    const float lad = __logf(dnum*rcd*rcd);
    const float y1 = inside? yv : x1;
    const float lv = inside? lad : 0.0f;

    out[(size_t)m*2]   = x0*mk;
    out[(size_t)m*2+1] = y1*mk;

    __shared__ float red[256];
    red[tid]=lv*mk;
    __syncthreads();
    #pragma unroll
    for(int s=128;s>0;s>>=1){ if(tid<s) red[tid]+=red[tid+s]; __syncthreads(); }
    if(tid==0) atomicAdd(&logdet[blockIdx.x>>5], red[0]);
}

extern "C" void kernel_launch(void* const* d_in, const int* in_sizes, int n_in,
                              void* d_out, int out_size, void* d_ws, size_t ws_size,
                              hipStream_t stream)
{
    const float* x      = (const float*)d_in[0];
    const float* mask   = (const float*)d_in[1];
    const float* w_pre  = (const float*)d_in[2];
    const float* b_pre  = (const float*)d_in[3];
    const float* dw_k   = (const float*)d_in[4];
    const float* dw_b   = (const float*)d_in[5];
    const float* w11    = (const float*)d_in[6];
    const float* b11    = (const float*)d_in[7];
    const float* ln1g   = (const float*)d_in[8];
    const float* ln1b   = (const float*)d_in[9];
    const float* ln2g   = (const float*)d_in[10];
    const float* ln2b   = (const float*)d_in[11];
    const float* w_proj = (const float*)d_in[12];
    const float* b_proj = (const float*)d_in[13];

    const size_t hbytes_bf16 = (size_t)MM*FF*2;        // 64 MiB each
    __hip_bfloat16* h0 = (__hip_bfloat16*)d_ws;
    __hip_bfloat16* h1 = h0 + (size_t)MM*FF;
    float* outp   = (float*)d_out;
    float* logdet = outp + (size_t)MM*2;

    const size_t wimg_bytes = (size_t)3*163840 + 20480;
    __hip_bfloat16* wimg;
    const bool ws_ok = (ws_size >= 2*hbytes_bf16 + wimg_bytes);
    if(ws_ok) wimg = (__hip_bfloat16*)((char*)d_ws + 2*hbytes_bf16);
    else      wimg = (__hip_bfloat16*)d_out;
    __hip_bfloat16* wpimg = wimg + (size_t)3*81920;

    wprep_kernel<<<32, 256, 0, stream>>>(w11, w_proj, wimg, wpimg);

    layer_kernel<1><<<MM/32, 256, 0, stream>>>(
        (const __hip_bfloat16*)nullptr, h1, x, w_pre, b_pre, mask,
        dw_k, dw_b, ln1g, ln1b, wimg, b11, ln2g, ln2b, 1);
    layer_kernel<0><<<MM/32, 256, 0, stream>>>(
        h1, h0, x, w_pre, b_pre, mask,
        dw_k + (size_t)3*FF, dw_b + (size_t)FF,
        ln1g + (size_t)FF, ln1b + (size_t)FF,
        wimg + (size_t)81920, b11 + (size_t)FF,
        ln2g + (size_t)FF, ln2b + (size_t)FF, 3);
    layer_kernel<0><<<MM/32, 256, 0, stream>>>(
        h0, h1, x, w_pre, b_pre, mask,
        dw_k + (size_t)6*FF, dw_b + (size_t)2*FF,
        ln1g + (size_t)2*FF, ln1b + (size_t)2*FF,
        wimg + (size_t)2*81920, b11 + (size_t)2*FF,
        ln2g + (size_t)2*FF, ln2b + (size_t)2*FF, 9);

    hipMemsetAsync(logdet, 0, BB*sizeof(float), stream);
    if(ws_ok){
        projspline_kernel<<<MM/128, 256, 0, stream>>>(h1, mask, wpimg, b_proj, x, outp, logdet);
    } else {
        float* P = (float*)d_ws;
        proj_kernel<<<MM/64, 256, 0, stream>>>(h1, mask, wpimg, b_proj, P);
        spline_kernel<<<MM/256, 256, 0, stream>>>(P, x, mask, outp, logdet);
    }
}

// Round 12
// 360.602 us; speedup vs baseline: 2.0836x; 2.0836x over previous
//
#include <hip/hip_runtime.h>
#include <hip/hip_bf16.h>
#include <cmath>

#define BB 16
#define TT 8192
#define MM (BB*TT)
#define FF 256
#define TBF 5.0f
#define PROJN 29

typedef __attribute__((ext_vector_type(8))) short short8;
typedef __attribute__((ext_vector_type(4))) float f32x4;

// tanh-form gelu: x*sigmoid(x*(c1 + c2*x^2)); max abs err vs exact ~3e-4.
__device__ __forceinline__ float gelu_fast(float x){
    const float x2 = x*x;
    const float v  = x*fmaf(0.07135481627f, x2, 1.595769122f);
    const float e  = __expf(-v);
    return x*__builtin_amdgcn_rcpf(1.0f + e);
}
__device__ __forceinline__ float softplusf_(float v){
    return fmaxf(v,0.0f) + log1pf(__expf(-fabsf(v)));
}
__device__ __forceinline__ unsigned pack2bf(float a, float b){
    __hip_bfloat16 ha = __float2bfloat16(a);
    __hip_bfloat16 hb = __float2bfloat16(b);
    const unsigned ua = *reinterpret_cast<const unsigned short*>(&ha);
    const unsigned ub = *reinterpret_cast<const unsigned short*>(&hb);
    return ua | (ub<<16);
}
__device__ __forceinline__ float bf2f(unsigned short u){
    unsigned v = ((unsigned)u)<<16;
    return *reinterpret_cast<float*>(&v);
}
__device__ __forceinline__ float4 unpack4(uint2 q){
    float4 f;
    f.x = bf2f((unsigned short)(q.x&0xffff)); f.y = bf2f((unsigned short)(q.x>>16));
    f.z = bf2f((unsigned short)(q.y&0xffff)); f.w = bf2f((unsigned short)(q.y>>16));
    return f;
}

// Layer images: wimg[layer][kc][n][40] bf16, [n][kp] = w11[kc*32+kp][n] (kp<32; pad 0).
// Proj image (blocks 24..31): wpimg[kc][n 0..31][40].
__global__ __launch_bounds__(256) void wprep_kernel(
    const float* __restrict__ w11, const float* __restrict__ wproj,
    __hip_bfloat16* __restrict__ wimg, __hip_bfloat16* __restrict__ wpimg)
{
    if(blockIdx.x < 24){
        const int layer = blockIdx.x>>3, kc = blockIdx.x&7;
        const float* __restrict__ w = w11 + (size_t)layer*FF*FF;
        __hip_bfloat16* __restrict__ o = wimg + (size_t)layer*81920 + kc*10240;
        for(int i=threadIdx.x; i<10240; i+=256){
            const int n = i/40, kp = i - n*40;
            const float v = (kp<32) ? w[(size_t)(kc*32+kp)*FF + n] : 0.0f;
            o[i] = __float2bfloat16(v);
        }
    } else {
        const int kc = blockIdx.x - 24;
        __hip_bfloat16* __restrict__ o = wpimg + (size_t)kc*1280;
        for(int i=threadIdx.x; i<1280; i+=256){
            const int n = i/40, kp = i - n*40;
            const float v = (kp<32 && n<PROJN) ? wproj[(size_t)(kc*32+kp)*PROJN + n] : 0.0f;
            o[i] = __float2bfloat16(v);
        }
    }
}

// One layer: 32 rows x 256 cols per block, 256 threads = 4 waves.
// Wave owns 32 rows x 64 cols (acc 2x4 = 32 acc regs). LDS ~18KB.
// launch_bounds(256,6): 512/6 = 85 regs/wave budget — fits ~80 needed, no spill;
// 6 blocks/CU = 24 waves/CU (75%). (256,8) = 64-reg budget SPILLED (round 11).
template<int PRE>
__global__ __launch_bounds__(256,6) void layer_kernel(
    const __hip_bfloat16* __restrict__ hbin, __hip_bfloat16* __restrict__ hbout,
    const float* __restrict__ xsrc,
    const float* __restrict__ w_pre, const float* __restrict__ b_pre,
    const float* __restrict__ mask,
    const float* __restrict__ dwk, const float* __restrict__ dwb,
    const float* __restrict__ g1, const float* __restrict__ b1,
    const __hip_bfloat16* __restrict__ wimgL, const float* __restrict__ b11,
    const float* __restrict__ g2, const float* __restrict__ b2,
    const int dil)
{
    __shared__ __hip_bfloat16 ytile[32][260];   // stride 260: conflict-free
    __shared__ float redS[32][4];
    __shared__ float redQ[32][4];
    __shared__ float stat[32][2];

    const int tid  = threadIdx.x;
    const int wave = tid>>6, lane = tid&63;
    const int l15  = lane&15, qq = lane>>4;

    int bid = blockIdx.x;                        // XCD swizzle (4096%8==0)
    bid = (bid&7)*((int)gridDim.x>>3) + (bid>>3);
    const int m0 = bid*32;
    const int b  = m0/TT;
    const int t0 = m0 - b*TT;
    const float* __restrict__ mrow = mask + (size_t)b*TT;

    // ---- Phase 1: conv + LN1 + gelu -> ytile. 8 rows/wave.
    const int f0 = lane*4;
    const float4 k0 = *(const float4*)&dwk[f0];
    const float4 k1 = *(const float4*)&dwk[FF+f0];
    const float4 k2 = *(const float4*)&dwk[2*FF+f0];
    const float4 cb = *(const float4*)&dwb[f0];
    const float4 g1v= *(const float4*)&g1[f0];
    const float4 b1v= *(const float4*)&b1[f0];
    float4 wp4, bp4;
    if(PRE){ wp4 = *(const float4*)&w_pre[f0]; bp4 = *(const float4*)&b_pre[f0]; }

    #pragma unroll 4
    for(int rr=0; rr<8; ++rr){
        const int r = wave*8+rr;
        const int m = m0+r, t = t0+r;
        const int okl = (t>=dil)   ? 1 : 0;
        const int okr = (t+dil<TT) ? 1 : 0;
        const int ml  = m - dil*okl;
        const int mr  = m + dil*okr;
        const float mkc = mrow[t];
        const float mkl = mrow[t - dil*okl] * (float)okl;
        const float mkr = mrow[t + dil*okr] * (float)okr;
        float4 hc, hl, hr;
        if(PRE){
            const float xc_ = xsrc[(size_t)m *2];
            const float xl_ = xsrc[(size_t)ml*2];
            const float xr_ = xsrc[(size_t)mr*2];
            hc.x=fmaf(xc_,wp4.x,bp4.x); hc.y=fmaf(xc_,wp4.y,bp4.y);
            hc.z=fmaf(xc_,wp4.z,bp4.z); hc.w=fmaf(xc_,wp4.w,bp4.w);
            hl.x=fmaf(xl_,wp4.x,bp4.x); hl.y=fmaf(xl_,wp4.y,bp4.y);
            hl.z=fmaf(xl_,wp4.z,bp4.z); hl.w=fmaf(xl_,wp4.w,bp4.w);
            hr.x=fmaf(xr_,wp4.x,bp4.x); hr.y=fmaf(xr_,wp4.y,bp4.y);
            hr.z=fmaf(xr_,wp4.z,bp4.z); hr.w=fmaf(xr_,wp4.w,bp4.w);
        } else {
            hc = unpack4(*(const uint2*)&hbin[(size_t)m *FF + f0]);
            hl = unpack4(*(const uint2*)&hbin[(size_t)ml*FF + f0]);
            hr = unpack4(*(const uint2*)&hbin[(size_t)mr*FF + f0]);
        }
        float4 a;
        a.x = fmaf(hc.x*mkc, k1.x, cb.x);
        a.y = fmaf(hc.y*mkc, k1.y, cb.y);
        a.z = fmaf(hc.z*mkc, k1.z, cb.z);
        a.w = fmaf(hc.w*mkc, k1.w, cb.w);
        a.x = fmaf(hl.x*mkl, k0.x, a.x);
        a.y = fmaf(hl.y*mkl, k0.y, a.y);
        a.z = fmaf(hl.z*mkl, k0.z, a.z);
        a.w = fmaf(hl.w*mkl, k0.w, a.w);
        a.x = fmaf(hr.x*mkr, k2.x, a.x);
        a.y = fmaf(hr.y*mkr, k2.y, a.y);
        a.z = fmaf(hr.z*mkr, k2.z, a.z);
        a.w = fmaf(hr.w*mkr, k2.w, a.w);
        float s  = a.x+a.y+a.z+a.w;
        float sq = fmaf(a.x,a.x, fmaf(a.y,a.y, fmaf(a.z,a.z, a.w*a.w)));
        #pragma unroll
        for(int o=32;o>0;o>>=1){
            s  += __shfl_xor(s,o,64);
            sq += __shfl_xor(sq,o,64);
        }
        const float mean = s*(1.0f/FF);
        const float var  = fmaf(-mean, mean, sq*(1.0f/FF));
        const float rs = rsqrtf(var + 1e-5f);
        const float y0 = gelu_fast(fmaf((a.x-mean)*rs, g1v.x, b1v.x));
        const float y1 = gelu_fast(fmaf((a.y-mean)*rs, g1v.y, b1v.y));
        const float y2 = gelu_fast(fmaf((a.z-mean)*rs, g1v.z, b1v.z));
        const float y3 = gelu_fast(fmaf((a.w-mean)*rs, g1v.w, b1v.w));
        *(uint2*)&ytile[r][f0] = make_uint2(pack2bf(y0,y1), pack2bf(y2,y3));
    }

    __syncthreads();

    // ---- Phase 2: MFMA GEMM. Wave owns 32 rows x cols [wave*64, wave*64+64).
    const int wc = wave*64;
    f32x4 acc[2][4];
    #pragma unroll
    for(int mf=0;mf<2;++mf)
        #pragma unroll
        for(int nf=0;nf<4;++nf)
            acc[mf][nf] = (f32x4){0.f,0.f,0.f,0.f};

    #pragma unroll
    for(int kc=0;kc<8;++kc){
        short8 bfv[4];
        #pragma unroll
        for(int nf=0;nf<4;++nf)
            bfv[nf] = *(const short8*)&wimgL[(size_t)kc*10240 + (wc+nf*16+l15)*40 + qq*8];
        short8 af[2];
        #pragma unroll
        for(int mf=0;mf<2;++mf)
            af[mf] = *(const short8*)&ytile[mf*16+l15][kc*32 + qq*8];
        #pragma unroll
        for(int nf=0;nf<4;++nf)
            #pragma unroll
            for(int mf=0;mf<2;++mf)
                acc[mf][nf] = __builtin_amdgcn_mfma_f32_16x16x32_bf16(af[mf], bfv[nf], acc[mf][nf], 0,0,0);
    }

    // ---- Phase 3: +b11, LN2 (cross-wave), gelu, residual, store bf16.
    float b11c[4], g2c[4], b2c[4], wpc[4], bpc[4];
    #pragma unroll
    for(int nf=0;nf<4;++nf){
        const int col = wc + nf*16 + l15;
        b11c[nf]=b11[col]; g2c[nf]=g2[col]; b2c[nf]=b2[col];
        if(PRE){ wpc[nf]=w_pre[col]; bpc[nf]=b_pre[col]; }
    }
    #pragma unroll
    for(int mf=0;mf<2;++mf){
        #pragma unroll
        for(int rg=0;rg<4;++rg){
            float s=0.f, sq=0.f;
            #pragma unroll
            for(int nf=0;nf<4;++nf){
                const float v = acc[mf][nf][rg] + b11c[nf];
                s += v; sq = fmaf(v,v,sq);
            }
            #pragma unroll
            for(int o=1;o<16;o<<=1){ s += __shfl_xor(s,o,64); sq += __shfl_xor(sq,o,64); }
            if(l15==0){
                const int row = mf*16 + qq*4 + rg;
                redS[row][wave]=s; redQ[row][wave]=sq;
            }
        }
    }
    __syncthreads();
    if(tid < 32){
        const float s  = redS[tid][0]+redS[tid][1]+redS[tid][2]+redS[tid][3];
        const float q2 = redQ[tid][0]+redQ[tid][1]+redQ[tid][2]+redQ[tid][3];
        const float mean = s*(1.0f/FF);
        const float var  = fmaf(-mean, mean, q2*(1.0f/FF));
        stat[tid][0]=mean; stat[tid][1]=rsqrtf(var+1e-5f);
    }
    __syncthreads();
    #pragma unroll
    for(int mf=0;mf<2;++mf){
        #pragma unroll
        for(int rg=0;rg<4;++rg){
            const int row = mf*16 + qq*4 + rg;
            const float mean = stat[row][0], rs = stat[row][1];
            const size_t gbase = (size_t)(m0+row)*FF;
            float x0r;
            if(PRE) x0r = xsrc[(size_t)(m0+row)*2];
            #pragma unroll
            for(int nf=0;nf<4;++nf){
                const int col = wc + nf*16 + l15;
                const float v  = acc[mf][nf][rg] + b11c[nf];
                const float yn = fmaf((v-mean)*rs, g2c[nf], b2c[nf]);
                float res;
                if(PRE) res = fmaf(x0r, wpc[nf], bpc[nf]);
                else    res = bf2f(*reinterpret_cast<const unsigned short*>(&hbin[gbase+col]));
                hbout[gbase+col] = __float2bfloat16(res + gelu_fast(yn));
            }
        }
    }
}

// ---------- Fused proj + spline: 128 rows/block ----------
__global__ __launch_bounds__(256,4) void projspline_kernel(
    const __hip_bfloat16* __restrict__ hbin, const float* __restrict__ mask,
    const __hip_bfloat16* __restrict__ wpimg, const float* __restrict__ bproj,
    const float* __restrict__ x, float* __restrict__ out,
    float* __restrict__ logdet)
{
    __shared__ __hip_bfloat16 ytile[32][260];
    __shared__ float Pl[128][33];
    __shared__ float red[256];

    const int tid = threadIdx.x;
    const int wave = tid>>6, lane = tid&63;
    const int l15 = lane&15, qq = lane>>4;
    const int m0 = blockIdx.x*128;
    const int f0 = lane*4;

    const int rh  = (wave&1)*16;          // row half within 32-row chunk
    const int wc2 = (wave>>1)*16;         // col group (0 or 16)
    const int col = wc2 + l15;            // 0..31
    const float bp = (col<PROJN)? bproj[col] : 0.0f;

    for(int chk=0; chk<4; ++chk){
        const int mc = m0 + chk*32;
        #pragma unroll
        for(int rr=0; rr<8; ++rr){
            const int r = wave*8+rr;
            const int m = mc+r;
            const float mk = mask[m];
            const float4 hc = unpack4(*(const uint2*)&hbin[(size_t)m*FF + f0]);
            *(uint2*)&ytile[r][f0] = make_uint2(pack2bf(hc.x*mk, hc.y*mk), pack2bf(hc.z*mk, hc.w*mk));
        }
        __syncthreads();

        f32x4 acc = (f32x4){0.f,0.f,0.f,0.f};
        #pragma unroll
        for(int kc=0;kc<8;++kc){
            const short8 bfv = *(const short8*)&wpimg[(size_t)kc*1280 + (wc2+l15)*40 + qq*8];
            const short8 af  = *(const short8*)&ytile[rh+l15][kc*32 + qq*8];
            acc = __builtin_amdgcn_mfma_f32_16x16x32_bf16(af, bfv, acc, 0,0,0);
        }
        #pragma unroll
        for(int rg=0;rg<4;++rg){
            const int row = rh + qq*4 + rg;
            const float mk = mask[mc+row];
            Pl[chk*32+row][col] = (acc[rg] + bp)*mk;
        }
        __syncthreads();
    }

    // ---- spline: rows 0..127 on threads 0..127
    float lv_mk = 0.0f;
    if(tid < 128){
        const int m = m0 + tid;
        float p[29];
        #pragma unroll
        for(int j=0;j<29;++j) p[j] = Pl[tid][j];
        const float x0 = x[(size_t)m*2];
        const float x1 = x[(size_t)m*2+1];
        const float mk = mask[m];
        const float sc = 0.0625f;

        float cw[11], ch_[11], d[11];
        {
            float mx=-1e30f;
            #pragma unroll
            for(int j=0;j<10;++j) mx = fmaxf(mx, p[j]);
            float e[10]; float se=0.f;
            #pragma unroll
            for(int j=0;j<10;++j){ e[j]=__expf((p[j]-mx)*sc); se+=e[j]; }
            const float inv = __builtin_amdgcn_rcpf(se);
            float cum=0.f;
            cw[0]=-TBF;
            #pragma unroll
            for(int j=0;j<10;++j){ cum += fmaf(0.99f, e[j]*inv, 0.001f); cw[j+1]=fmaf(2.0f*TBF,cum,-TBF); }
            cw[10]=TBF;
        }
        {
            float mx=-1e30f;
            #pragma unroll
            for(int j=0;j<10;++j) mx = fmaxf(mx, p[10+j]);
            float e[10]; float se=0.f;
            #pragma unroll
            for(int j=0;j<10;++j){ e[j]=__expf((p[10+j]-mx)*sc); se+=e[j]; }
            const float inv = __builtin_amdgcn_rcpf(se);
            float cum=0.f;
            ch_[0]=-TBF;
            #pragma unroll
            for(int j=0;j<10;++j){ cum += fmaf(0.99f, e[j]*inv, 0.001f); ch_[j+1]=fmaf(2.0f*TBF,cum,-TBF); }
            ch_[10]=TBF;
        }
        d[0]=1.0f; d[10]=1.0f;
        #pragma unroll
        for(int k=1;k<10;++k) d[k] = 0.001f + softplusf_(p[19+k]);

        const bool inside = (x1>=-TBF)&&(x1<=TBF);
        const float xc = fminf(fmaxf(x1,-TBF),TBF);

        float icw=cw[0], ibw=cw[1]-cw[0], ich=ch_[0], ibh=ch_[1]-ch_[0], dk=d[0], dk1=d[1];
        #pragma unroll
        for(int j=1;j<10;++j){
            const bool sel = (xc>=cw[j]);
            icw = sel? cw[j]        : icw;
            ibw = sel? cw[j+1]-cw[j]: ibw;
            ich = sel? ch_[j]       : ich;
            ibh = sel? ch_[j+1]-ch_[j]: ibh;
            dk  = sel? d[j]         : dk;
            dk1 = sel? d[j+1]       : dk1;
        }

        const float delta = __fdividef(ibh, ibw);
        const float th = __fdividef(xc-icw, ibw);
        const float th1m = th*(1.0f-th);
        const float denom = fmaf(fmaf(-2.0f,delta,dk+dk1), th1m, delta);
        const float num = ibh*fmaf(delta*th, th, dk*th1m);
        const float rcd = __builtin_amdgcn_rcpf(denom);
        const float yv = ich + num*rcd;
        const float omt = 1.0f-th;
        const float dnum = delta*delta*(dk1*th*th + 2.0f*delta*th1m + dk*omt*omt);
        const float lad = __logf(dnum*rcd*rcd);
        const float y1 = inside? yv : x1;
        const float lv = inside? lad : 0.0f;

        out[(size_t)m*2]   = x0*mk;
        out[(size_t)m*2+1] = y1*mk;
        lv_mk = lv*mk;
    }

    red[tid] = lv_mk;
    __syncthreads();
    #pragma unroll
    for(int s=128;s>0;s>>=1){ if(tid<s) red[tid]+=red[tid+s]; __syncthreads(); }
    if(tid==0) atomicAdd(&logdet[blockIdx.x>>6], red[0]);   // 64 blocks / batch
}

// ---------- Fallback pair (used only if ws can't host wimg) ----------
__global__ __launch_bounds__(256,4) void proj_kernel(
    const __hip_bfloat16* __restrict__ hbin, const float* __restrict__ mask,
    const __hip_bfloat16* __restrict__ wpimg, const float* __restrict__ bproj,
    float* __restrict__ P)
{
    __shared__ __hip_bfloat16 ytile[64][260];
    const int tid = threadIdx.x;
    const int wave = tid>>6, lane = tid&63;
    const int l15 = lane&15, qq = lane>>4;
    const int m0 = blockIdx.x*64;
    const int f0 = lane*4;

    #pragma unroll 4
    for(int rr=0; rr<16; ++rr){
        const int r = wave*16+rr;
        const int m = m0+r;
        const float mk = mask[m];
        const float4 hc = unpack4(*(const uint2*)&hbin[(size_t)m*FF + f0]);
        *(uint2*)&ytile[r][f0] = make_uint2(pack2bf(hc.x*mk, hc.y*mk), pack2bf(hc.z*mk, hc.w*mk));
    }
    __syncthreads();

    const int rh = (wave&1)*32, wc2 = (wave>>1)*16;
    f32x4 acc[2];
    acc[0] = (f32x4){0.f,0.f,0.f,0.f};
    acc[1] = (f32x4){0.f,0.f,0.f,0.f};
    #pragma unroll
    for(int kc=0;kc<8;++kc){
        const short8 bfv = *(const short8*)&wpimg[(size_t)kc*1280 + (wc2+l15)*40 + qq*8];
        #pragma unroll
        for(int mf=0;mf<2;++mf){
            const short8 af = *(const short8*)&ytile[rh+mf*16+l15][kc*32 + qq*8];
            acc[mf] = __builtin_amdgcn_mfma_f32_16x16x32_bf16(af, bfv, acc[mf], 0,0,0);
        }
    }
    const int col = wc2 + l15;
    const float bp = (col<PROJN)? bproj[col] : 0.0f;
    #pragma unroll
    for(int mf=0;mf<2;++mf){
        #pragma unroll
        for(int rg=0;rg<4;++rg){
            const int row = rh + mf*16 + qq*4 + rg;
            const float mk = mask[m0+row];
            P[(size_t)(m0+row)*32 + col] = (acc[mf][rg] + bp)*mk;
        }
    }
}

__global__ __launch_bounds__(256) void spline_kernel(
    const float* __restrict__ P, const float* __restrict__ x,
    const float* __restrict__ mask, float* __restrict__ out,
    float* __restrict__ logdet)
{
    const int tid = threadIdx.x;
    const int m = blockIdx.x*256 + tid;
    float p[32];
    #pragma unroll
    for(int j=0;j<8;++j) ((float4*)p)[j] = ((const float4*)P)[(size_t)m*8+j];
    const float x0 = x[(size_t)m*2];
    const float x1 = x[(size_t)m*2+1];
    const float mk = mask[m];
    const float sc = 0.0625f;

    float cw[11], ch_[11], d[11];
    {
        float mx=-1e30f;
        #pragma unroll
        for(int j=0;j<10;++j) mx = fmaxf(mx, p[j]);
        float e[10]; float se=0.f;
        #pragma unroll
        for(int j=0;j<10;++j){ e[j]=__expf((p[j]-mx)*sc); se+=e[j]; }
        const float inv = __builtin_amdgcn_rcpf(se);
        float cum=0.f;
        cw[0]=-TBF;
        #pragma unroll
        for(int j=0;j<10;++j){ cum += fmaf(0.99f, e[j]*inv, 0.001f); cw[j+1]=fmaf(2.0f*TBF,cum,-TBF); }
        cw[10]=TBF;
    }
    {
        float mx=-1e30f;
        #pragma unroll
        for(int j=0;j<10;++j) mx = fmaxf(mx, p[10+j]);
        float e[10]; float se=0.f;
        #pragma unroll
        for(int j=0;j<10;++j){ e[j]=__expf((p[10+j]-mx)*sc); se+=e[j]; }
        const float inv = __builtin_amdgcn_rcpf(se);
        float cum=0.f;
        ch_[0]=-TBF;
        #pragma unroll
        for(int j=0;j<10;++j){ cum += fmaf(0.99f, e[j]*inv, 0.001f); ch_[j+1]=fmaf(2.0f*TBF,cum,-TBF); }
        ch_[10]=TBF;
    }
    d[0]=1.0f; d[10]=1.0f;
    #pragma unroll
    for(int k=1;k<10;++k) d[k] = 0.001f + softplusf_(p[19+k]);

    const bool inside = (x1>=-TBF)&&(x1<=TBF);
    const float xc = fminf(fmaxf(x1,-TBF),TBF);

    float icw=cw[0], ibw=cw[1]-cw[0], ich=ch_[0], ibh=ch_[1]-ch_[0], dk=d[0], dk1=d[1];
    #pragma unroll
    for(int j=1;j<10;++j){
        const bool sel = (xc>=cw[j]);
        icw = sel? cw[j]        : icw;
        ibw = sel? cw[j+1]-cw[j]: ibw;
        ich = sel? ch_[j]       : ich;
        ibh = sel? ch_[j+1]-ch_[j]: ibh;
        dk  = sel? d[j]         : dk;
        dk1 = sel? d[j+1]       : dk1;
    }

    const float delta = __fdividef(ibh, ibw);
    const float th = __fdividef(xc-icw, ibw);
    const float th1m = th*(1.0f-th);
    const float denom = fmaf(fmaf(-2.0f,delta,dk+dk1), th1m, delta);
    const float num = ibh*fmaf(delta*th, th, dk*th1m);
    const float rcd = __builtin_amdgcn_rcpf(denom);
    const float yv = ich + num*rcd;
    const float omt = 1.0f-th;
    const float dnum = delta*delta*(dk1*th*th + 2.0f*delta*th1m + dk*omt*omt);
    const float lad = __logf(dnum*rcd*rcd);
    const float y1 = inside? yv : x1;
    const float lv = inside? lad : 0.0f;

    out[(size_t)m*2]   = x0*mk;
    out[(size_t)m*2+1] = y1*mk;

    __shared__ float red[256];
    red[tid]=lv*mk;
    __syncthreads();
    #pragma unroll
    for(int s=128;s>0;s>>=1){ if(tid<s) red[tid]+=red[tid+s]; __syncthreads(); }
    if(tid==0) atomicAdd(&logdet[blockIdx.x>>5], red[0]);
}

extern "C" void kernel_launch(void* const* d_in, const int* in_sizes, int n_in,
                              void* d_out, int out_size, void* d_ws, size_t ws_size,
                              hipStream_t stream)
{
    const float* x      = (const float*)d_in[0];
    const float* mask   = (const float*)d_in[1];
    const float* w_pre  = (const float*)d_in[2];
    const float* b_pre  = (const float*)d_in[3];
    const float* dw_k   = (const float*)d_in[4];
    const float* dw_b   = (const float*)d_in[5];
    const float* w11    = (const float*)d_in[6];
    const float* b11    = (const float*)d_in[7];
    const float* ln1g   = (const float*)d_in[8];
    const float* ln1b   = (const float*)d_in[9];
    const float* ln2g   = (const float*)d_in[10];
    const float* ln2b   = (const float*)d_in[11];
    const float* w_proj = (const float*)d_in[12];
    const float* b_proj = (const float*)d_in[13];

    const size_t hbytes_bf16 = (size_t)MM*FF*2;        // 64 MiB each
    __hip_bfloat16* h0 = (__hip_bfloat16*)d_ws;
    __hip_bfloat16* h1 = h0 + (size_t)MM*FF;
    float* outp   = (float*)d_out;
    float* logdet = outp + (size_t)MM*2;

    const size_t wimg_bytes = (size_t)3*163840 + 20480;
    __hip_bfloat16* wimg;
    const bool ws_ok = (ws_size >= 2*hbytes_bf16 + wimg_bytes);
    if(ws_ok) wimg = (__hip_bfloat16*)((char*)d_ws + 2*hbytes_bf16);
    else      wimg = (__hip_bfloat16*)d_out;
    __hip_bfloat16* wpimg = wimg + (size_t)3*81920;

    wprep_kernel<<<32, 256, 0, stream>>>(w11, w_proj, wimg, wpimg);

    layer_kernel<1><<<MM/32, 256, 0, stream>>>(
        (const __hip_bfloat16*)nullptr, h1, x, w_pre, b_pre, mask,
        dw_k, dw_b, ln1g, ln1b, wimg, b11, ln2g, ln2b, 1);
    layer_kernel<0><<<MM/32, 256, 0, stream>>>(
        h1, h0, x, w_pre, b_pre, mask,
        dw_k + (size_t)3*FF, dw_b + (size_t)FF,
        ln1g + (size_t)FF, ln1b + (size_t)FF,
        wimg + (size_t)81920, b11 + (size_t)FF,
        ln2g + (size_t)FF, ln2b + (size_t)FF, 3);
    layer_kernel<0><<<MM/32, 256, 0, stream>>>(
        h0, h1, x, w_pre, b_pre, mask,
        dw_k + (size_t)6*FF, dw_b + (size_t)2*FF,
        ln1g + (size_t)2*FF, ln1b + (size_t)2*FF,
        wimg + (size_t)2*81920, b11 + (size_t)2*FF,
        ln2g + (size_t)2*FF, ln2b + (size_t)2*FF, 9);

    hipMemsetAsync(logdet, 0, BB*sizeof(float), stream);
    if(ws_ok){
        projspline_kernel<<<MM/128, 256, 0, stream>>>(h1, mask, wpimg, b_proj, x, outp, logdet);
    } else {
        float* P = (float*)d_ws;
        proj_kernel<<<MM/64, 256, 0, stream>>>(h1, mask, wpimg, b_proj, P);
        spline_kernel<<<MM/256, 256, 0, stream>>>(P, x, mask, outp, logdet);
    }
}

// Round 13
// 330.523 us; speedup vs baseline: 2.2732x; 1.0910x over previous
//
#include <hip/hip_runtime.h>
#include <hip/hip_bf16.h>
#include <cmath>

#define BB 16
#define TT 8192
#define MM (BB*TT)
#define FF 256
#define TBF 5.0f
#define PROJN 29

typedef __attribute__((ext_vector_type(8))) short short8;
typedef __attribute__((ext_vector_type(4))) float f32x4;

// tanh-form gelu: x*sigmoid(x*(c1 + c2*x^2)); max abs err vs exact ~3e-4.
__device__ __forceinline__ float gelu_fast(float x){
    const float x2 = x*x;
    const float v  = x*fmaf(0.07135481627f, x2, 1.595769122f);
    const float e  = __expf(-v);
    return x*__builtin_amdgcn_rcpf(1.0f + e);
}
__device__ __forceinline__ float softplusf_(float v){
    return fmaxf(v,0.0f) + log1pf(__expf(-fabsf(v)));
}
__device__ __forceinline__ unsigned pack2bf(float a, float b){
    __hip_bfloat16 ha = __float2bfloat16(a);
    __hip_bfloat16 hb = __float2bfloat16(b);
    const unsigned ua = *reinterpret_cast<const unsigned short*>(&ha);
    const unsigned ub = *reinterpret_cast<const unsigned short*>(&hb);
    return ua | (ub<<16);
}
__device__ __forceinline__ float bf2f(unsigned short u){
    unsigned v = ((unsigned)u)<<16;
    return *reinterpret_cast<float*>(&v);
}
__device__ __forceinline__ float4 unpack4(uint2 q){
    float4 f;
    f.x = bf2f((unsigned short)(q.x&0xffff)); f.y = bf2f((unsigned short)(q.x>>16));
    f.z = bf2f((unsigned short)(q.y&0xffff)); f.w = bf2f((unsigned short)(q.y>>16));
    return f;
}

// Layer images: wimg[layer][kc][n][40] bf16, [n][kp] = w11[kc*32+kp][n] (kp<32; pad 0).
// Proj image (blocks 24..31): wpimg[kc][n 0..31][40].
__global__ __launch_bounds__(256) void wprep_kernel(
    const float* __restrict__ w11, const float* __restrict__ wproj,
    __hip_bfloat16* __restrict__ wimg, __hip_bfloat16* __restrict__ wpimg)
{
    if(blockIdx.x < 24){
        const int layer = blockIdx.x>>3, kc = blockIdx.x&7;
        const float* __restrict__ w = w11 + (size_t)layer*FF*FF;
        __hip_bfloat16* __restrict__ o = wimg + (size_t)layer*81920 + kc*10240;
        for(int i=threadIdx.x; i<10240; i+=256){
            const int n = i/40, kp = i - n*40;
            const float v = (kp<32) ? w[(size_t)(kc*32+kp)*FF + n] : 0.0f;
            o[i] = __float2bfloat16(v);
        }
    } else {
        const int kc = blockIdx.x - 24;
        __hip_bfloat16* __restrict__ o = wpimg + (size_t)kc*1280;
        for(int i=threadIdx.x; i<1280; i+=256){
            const int n = i/40, kp = i - n*40;
            const float v = (kp<32 && n<PROJN) ? wproj[(size_t)(kc*32+kp)*PROJN + n] : 0.0f;
            o[i] = __float2bfloat16(v);
        }
    }
}

// One layer: 32 rows x 256 cols per block, 256 threads = 4 waves. (Round-9 config:
// hstash residual in LDS, (256,4) -> 60 VGPR no spill, 4 blocks/CU. Rounds 10-12
// showed exceeding 16 waves/CU breaks the register file or write-combining.)
__global__ __launch_bounds__(256,4) void layer_kernel(
    const __hip_bfloat16* __restrict__ hbin, __hip_bfloat16* __restrict__ hbout,
    const float* __restrict__ xsrc,
    const float* __restrict__ w_pre, const float* __restrict__ b_pre,
    const float* __restrict__ mask,
    const float* __restrict__ dwk, const float* __restrict__ dwb,
    const float* __restrict__ g1, const float* __restrict__ b1,
    const __hip_bfloat16* __restrict__ wimgL, const float* __restrict__ b11,
    const float* __restrict__ g2, const float* __restrict__ b2,
    const int dil, const int pre_mode)
{
    __shared__ __hip_bfloat16 ytile[32][260];   // stride 260: conflict-free
    __shared__ __hip_bfloat16 hstash[32][260];
    __shared__ float redS[32][4];
    __shared__ float redQ[32][4];
    __shared__ float stat[32][2];

    const int tid  = threadIdx.x;
    const int wave = tid>>6, lane = tid&63;
    const int l15  = lane&15, qq = lane>>4;

    int bid = blockIdx.x;                        // XCD swizzle (4096%8==0)
    bid = (bid&7)*((int)gridDim.x>>3) + (bid>>3);
    const int m0 = bid*32;
    const int b  = m0/TT;
    const int t0 = m0 - b*TT;
    const float* __restrict__ mrow = mask + (size_t)b*TT;

    // ---- Phase 1: conv + LN1 + gelu -> ytile; stash center h -> hstash.
    const int f0 = lane*4;
    const float4 k0 = *(const float4*)&dwk[f0];
    const float4 k1 = *(const float4*)&dwk[FF+f0];
    const float4 k2 = *(const float4*)&dwk[2*FF+f0];
    const float4 cb = *(const float4*)&dwb[f0];
    const float4 g1v= *(const float4*)&g1[f0];
    const float4 b1v= *(const float4*)&b1[f0];
    float4 wp4, bp4;
    if(pre_mode){ wp4 = *(const float4*)&w_pre[f0]; bp4 = *(const float4*)&b_pre[f0]; }

    #pragma unroll 4
    for(int rr=0; rr<8; ++rr){
        const int r = wave*8+rr;
        const int m = m0+r, t = t0+r;
        const int okl = (t>=dil)   ? 1 : 0;
        const int okr = (t+dil<TT) ? 1 : 0;
        const int ml  = m - dil*okl;
        const int mr  = m + dil*okr;
        const float mkc = mrow[t];
        const float mkl = mrow[t - dil*okl] * (float)okl;
        const float mkr = mrow[t + dil*okr] * (float)okr;
        float4 hc, hl, hr;
        uint2 hcraw;
        if(pre_mode){
            const float xc_ = xsrc[(size_t)m *2];
            const float xl_ = xsrc[(size_t)ml*2];
            const float xr_ = xsrc[(size_t)mr*2];
            hc.x=fmaf(xc_,wp4.x,bp4.x); hc.y=fmaf(xc_,wp4.y,bp4.y);
            hc.z=fmaf(xc_,wp4.z,bp4.z); hc.w=fmaf(xc_,wp4.w,bp4.w);
            hl.x=fmaf(xl_,wp4.x,bp4.x); hl.y=fmaf(xl_,wp4.y,bp4.y);
            hl.z=fmaf(xl_,wp4.z,bp4.z); hl.w=fmaf(xl_,wp4.w,bp4.w);
            hr.x=fmaf(xr_,wp4.x,bp4.x); hr.y=fmaf(xr_,wp4.y,bp4.y);
            hr.z=fmaf(xr_,wp4.z,bp4.z); hr.w=fmaf(xr_,wp4.w,bp4.w);
            hcraw = make_uint2(pack2bf(hc.x,hc.y), pack2bf(hc.z,hc.w));
        } else {
            hcraw          = *(const uint2*)&hbin[(size_t)m *FF + f0];
            const uint2 ql = *(const uint2*)&hbin[(size_t)ml*FF + f0];
            const uint2 qr = *(const uint2*)&hbin[(size_t)mr*FF + f0];
            hc = unpack4(hcraw); hl = unpack4(ql); hr = unpack4(qr);
        }
        *(uint2*)&hstash[r][f0] = hcraw;
        float4 a;
        a.x = fmaf(hc.x*mkc, k1.x, cb.x);
        a.y = fmaf(hc.y*mkc, k1.y, cb.y);
        a.z = fmaf(hc.z*mkc, k1.z, cb.z);
        a.w = fmaf(hc.w*mkc, k1.w, cb.w);
        a.x = fmaf(hl.x*mkl, k0.x, a.x);
        a.y = fmaf(hl.y*mkl, k0.y, a.y);
        a.z = fmaf(hl.z*mkl, k0.z, a.z);
        a.w = fmaf(hl.w*mkl, k0.w, a.w);
        a.x = fmaf(hr.x*mkr, k2.x, a.x);
        a.y = fmaf(hr.y*mkr, k2.y, a.y);
        a.z = fmaf(hr.z*mkr, k2.z, a.z);
        a.w = fmaf(hr.w*mkr, k2.w, a.w);
        float s  = a.x+a.y+a.z+a.w;
        float sq = fmaf(a.x,a.x, fmaf(a.y,a.y, fmaf(a.z,a.z, a.w*a.w)));
        #pragma unroll
        for(int o=32;o>0;o>>=1){
            s  += __shfl_xor(s,o,64);
            sq += __shfl_xor(sq,o,64);
        }
        const float mean = s*(1.0f/FF);
        const float var  = fmaf(-mean, mean, sq*(1.0f/FF));
        const float rs = rsqrtf(var + 1e-5f);
        const float y0 = gelu_fast(fmaf((a.x-mean)*rs, g1v.x, b1v.x));
        const float y1 = gelu_fast(fmaf((a.y-mean)*rs, g1v.y, b1v.y));
        const float y2 = gelu_fast(fmaf((a.z-mean)*rs, g1v.z, b1v.z));
        const float y3 = gelu_fast(fmaf((a.w-mean)*rs, g1v.w, b1v.w));
        *(uint2*)&ytile[r][f0] = make_uint2(pack2bf(y0,y1), pack2bf(y2,y3));
    }

    __syncthreads();

    // ---- Phase 2: MFMA GEMM. Wave owns 32 rows x cols [wave*64, wave*64+64).
    const int wc = wave*64;
    f32x4 acc[2][4];
    #pragma unroll
    for(int mf=0;mf<2;++mf)
        #pragma unroll
        for(int nf=0;nf<4;++nf)
            acc[mf][nf] = (f32x4){0.f,0.f,0.f,0.f};

    #pragma unroll
    for(int kc=0;kc<8;++kc){
        short8 bfv[4];
        #pragma unroll
        for(int nf=0;nf<4;++nf)
            bfv[nf] = *(const short8*)&wimgL[(size_t)kc*10240 + (wc+nf*16+l15)*40 + qq*8];
        short8 af[2];
        #pragma unroll
        for(int mf=0;mf<2;++mf)
            af[mf] = *(const short8*)&ytile[mf*16+l15][kc*32 + qq*8];
        #pragma unroll
        for(int nf=0;nf<4;++nf)
            #pragma unroll
            for(int mf=0;mf<2;++mf)
                acc[mf][nf] = __builtin_amdgcn_mfma_f32_16x16x32_bf16(af[mf], bfv[nf], acc[mf][nf], 0,0,0);
    }

    // ---- Phase 3: +b11, LN2 (cross-wave), gelu, residual from hstash, store bf16.
    float b11c[4], g2c[4], b2c[4];
    #pragma unroll
    for(int nf=0;nf<4;++nf){
        const int col = wc + nf*16 + l15;
        b11c[nf]=b11[col]; g2c[nf]=g2[col]; b2c[nf]=b2[col];
    }
    #pragma unroll
    for(int mf=0;mf<2;++mf){
        #pragma unroll
        for(int rg=0;rg<4;++rg){
            float s=0.f, sq=0.f;
            #pragma unroll
            for(int nf=0;nf<4;++nf){
                const float v = acc[mf][nf][rg] + b11c[nf];
                s += v; sq = fmaf(v,v,sq);
            }
            #pragma unroll
            for(int o=1;o<16;o<<=1){ s += __shfl_xor(s,o,64); sq += __shfl_xor(sq,o,64); }
            if(l15==0){
                const int row = mf*16 + qq*4 + rg;
                redS[row][wave]=s; redQ[row][wave]=sq;
            }
        }
    }
    __syncthreads();
    if(tid < 32){
        const float s  = redS[tid][0]+redS[tid][1]+redS[tid][2]+redS[tid][3];
        const float q2 = redQ[tid][0]+redQ[tid][1]+redQ[tid][2]+redQ[tid][3];
        const float mean = s*(1.0f/FF);
        const float var  = fmaf(-mean, mean, q2*(1.0f/FF));
        stat[tid][0]=mean; stat[tid][1]=rsqrtf(var+1e-5f);
    }
    __syncthreads();
    #pragma unroll
    for(int mf=0;mf<2;++mf){
        #pragma unroll
        for(int rg=0;rg<4;++rg){
            const int row = mf*16 + qq*4 + rg;
            const float mean = stat[row][0], rs = stat[row][1];
            const size_t gbase = (size_t)(m0+row)*FF;
            #pragma unroll
            for(int nf=0;nf<4;++nf){
                const int col = wc + nf*16 + l15;
                const float v  = acc[mf][nf][rg] + b11c[nf];
                const float yn = fmaf((v-mean)*rs, g2c[nf], b2c[nf]);
                const float res = bf2f(*reinterpret_cast<const unsigned short*>(&hstash[row][col]));
                hbout[gbase+col] = __float2bfloat16(res + gelu_fast(yn));
            }
        }
    }
}

// ---------- Fused proj + spline: 128 rows/block (validated rounds 11/12) ----------
__global__ __launch_bounds__(256,4) void projspline_kernel(
    const __hip_bfloat16* __restrict__ hbin, const float* __restrict__ mask,
    const __hip_bfloat16* __restrict__ wpimg, const float* __restrict__ bproj,
    const float* __restrict__ x, float* __restrict__ out,
    float* __restrict__ logdet)
{
    __shared__ __hip_bfloat16 ytile[32][260];
    __shared__ float Pl[128][33];
    __shared__ float red[256];

    const int tid = threadIdx.x;
    const int wave = tid>>6, lane = tid&63;
    const int l15 = lane&15, qq = lane>>4;
    const int m0 = blockIdx.x*128;
    const int f0 = lane*4;

    const int rh  = (wave&1)*16;          // row half within 32-row chunk
    const int wc2 = (wave>>1)*16;         // col group (0 or 16)
    const int col = wc2 + l15;            // 0..31
    const float bp = (col<PROJN)? bproj[col] : 0.0f;

    for(int chk=0; chk<4; ++chk){
        const int mc = m0 + chk*32;
        #pragma unroll
        for(int rr=0; rr<8; ++rr){
            const int r = wave*8+rr;
            const int m = mc+r;
            const float mk = mask[m];
            const float4 hc = unpack4(*(const uint2*)&hbin[(size_t)m*FF + f0]);
            *(uint2*)&ytile[r][f0] = make_uint2(pack2bf(hc.x*mk, hc.y*mk), pack2bf(hc.z*mk, hc.w*mk));
        }
        __syncthreads();

        f32x4 acc = (f32x4){0.f,0.f,0.f,0.f};
        #pragma unroll
        for(int kc=0;kc<8;++kc){
            const short8 bfv = *(const short8*)&wpimg[(size_t)kc*1280 + (wc2+l15)*40 + qq*8];
            const short8 af  = *(const short8*)&ytile[rh+l15][kc*32 + qq*8];
            acc = __builtin_amdgcn_mfma_f32_16x16x32_bf16(af, bfv, acc, 0,0,0);
        }
        #pragma unroll
        for(int rg=0;rg<4;++rg){
            const int row = rh + qq*4 + rg;
            const float mk = mask[mc+row];
            Pl[chk*32+row][col] = (acc[rg] + bp)*mk;
        }
        __syncthreads();
    }

    // ---- spline: rows 0..127 on threads 0..127
    float lv_mk = 0.0f;
    if(tid < 128){
        const int m = m0 + tid;
        float p[29];
        #pragma unroll
        for(int j=0;j<29;++j) p[j] = Pl[tid][j];
        const float x0 = x[(size_t)m*2];
        const float x1 = x[(size_t)m*2+1];
        const float mk = mask[m];
        const float sc = 0.0625f;

        float cw[11], ch_[11], d[11];
        {
            float mx=-1e30f;
            #pragma unroll
            for(int j=0;j<10;++j) mx = fmaxf(mx, p[j]);
            float e[10]; float se=0.f;
            #pragma unroll
            for(int j=0;j<10;++j){ e[j]=__expf((p[j]-mx)*sc); se+=e[j]; }
            const float inv = __builtin_amdgcn_rcpf(se);
            float cum=0.f;
            cw[0]=-TBF;
            #pragma unroll
            for(int j=0;j<10;++j){ cum += fmaf(0.99f, e[j]*inv, 0.001f); cw[j+1]=fmaf(2.0f*TBF,cum,-TBF); }
            cw[10]=TBF;
        }
        {
            float mx=-1e30f;
            #pragma unroll
            for(int j=0;j<10;++j) mx = fmaxf(mx, p[10+j]);
            float e[10]; float se=0.f;
            #pragma unroll
            for(int j=0;j<10;++j){ e[j]=__expf((p[10+j]-mx)*sc); se+=e[j]; }
            const float inv = __builtin_amdgcn_rcpf(se);
            float cum=0.f;
            ch_[0]=-TBF;
            #pragma unroll
            for(int j=0;j<10;++j){ cum += fmaf(0.99f, e[j]*inv, 0.001f); ch_[j+1]=fmaf(2.0f*TBF,cum,-TBF); }
            ch_[10]=TBF;
        }
        d[0]=1.0f; d[10]=1.0f;
        #pragma unroll
        for(int k=1;k<10;++k) d[k] = 0.001f + softplusf_(p[19+k]);

        const bool inside = (x1>=-TBF)&&(x1<=TBF);
        const float xc = fminf(fmaxf(x1,-TBF),TBF);

        float icw=cw[0], ibw=cw[1]-cw[0], ich=ch_[0], ibh=ch_[1]-ch_[0], dk=d[0], dk1=d[1];
        #pragma unroll
        for(int j=1;j<10;++j){
            const bool sel = (xc>=cw[j]);
            icw = sel? cw[j]        : icw;
            ibw = sel? cw[j+1]-cw[j]: ibw;
            ich = sel? ch_[j]       : ich;
            ibh = sel? ch_[j+1]-ch_[j]: ibh;
            dk  = sel? d[j]         : dk;
            dk1 = sel? d[j+1]       : dk1;
        }

        const float delta = __fdividef(ibh, ibw);
        const float th = __fdividef(xc-icw, ibw);
        const float th1m = th*(1.0f-th);
        const float denom = fmaf(fmaf(-2.0f,delta,dk+dk1), th1m, delta);
        const float num = ibh*fmaf(delta*th, th, dk*th1m);
        const float rcd = __builtin_amdgcn_rcpf(denom);
        const float yv = ich + num*rcd;
        const float omt = 1.0f-th;
        const float dnum = delta*delta*(dk1*th*th + 2.0f*delta*th1m + dk*omt*omt);
        const float lad = __logf(dnum*rcd*rcd);
        const float y1 = inside? yv : x1;
        const float lv = inside? lad : 0.0f;

        out[(size_t)m*2]   = x0*mk;
        out[(size_t)m*2+1] = y1*mk;
        lv_mk = lv*mk;
    }

    red[tid] = lv_mk;
    __syncthreads();
    #pragma unroll
    for(int s=128;s>0;s>>=1){ if(tid<s) red[tid]+=red[tid+s]; __syncthreads(); }
    if(tid==0) atomicAdd(&logdet[blockIdx.x>>6], red[0]);   // 64 blocks / batch
}

// ---------- Fallback pair (used only if ws can't host wimg) ----------
__global__ __launch_bounds__(256,4) void proj_kernel(
    const __hip_bfloat16* __restrict__ hbin, const float* __restrict__ mask,
    const __hip_bfloat16* __restrict__ wpimg, const float* __restrict__ bproj,
    float* __restrict__ P)
{
    __shared__ __hip_bfloat16 ytile[64][260];
    const int tid = threadIdx.x;
    const int wave = tid>>6, lane = tid&63;
    const int l15 = lane&15, qq = lane>>4;
    const int m0 = blockIdx.x*64;
    const int f0 = lane*4;

    #pragma unroll 4
    for(int rr=0; rr<16; ++rr){
        const int r = wave*16+rr;
        const int m = m0+r;
        const float mk = mask[m];
        const float4 hc = unpack4(*(const uint2*)&hbin[(size_t)m*FF + f0]);
        *(uint2*)&ytile[r][f0] = make_uint2(pack2bf(hc.x*mk, hc.y*mk), pack2bf(hc.z*mk, hc.w*mk));
    }
    __syncthreads();

    const int rh = (wave&1)*32, wc2 = (wave>>1)*16;
    f32x4 acc[2];
    acc[0] = (f32x4){0.f,0.f,0.f,0.f};
    acc[1] = (f32x4){0.f,0.f,0.f,0.f};
    #pragma unroll
    for(int kc=0;kc<8;++kc){
        const short8 bfv = *(const short8*)&wpimg[(size_t)kc*1280 + (wc2+l15)*40 + qq*8];
        #pragma unroll
        for(int mf=0;mf<2;++mf){
            const short8 af = *(const short8*)&ytile[rh+mf*16+l15][kc*32 + qq*8];
            acc[mf] = __builtin_amdgcn_mfma_f32_16x16x32_bf16(af, bfv, acc[mf], 0,0,0);
        }
    }
    const int col = wc2 + l15;
    const float bp = (col<PROJN)? bproj[col] : 0.0f;
    #pragma unroll
    for(int mf=0;mf<2;++mf){
        #pragma unroll
        for(int rg=0;rg<4;++rg){
            const int row = rh + mf*16 + qq*4 + rg;
            const float mk = mask[m0+row];
            P[(size_t)(m0+row)*32 + col] = (acc[mf][rg] + bp)*mk;
        }
    }
}

__global__ __launch_bounds__(256) void spline_kernel(
    const float* __restrict__ P, const float* __restrict__ x,
    const float* __restrict__ mask, float* __restrict__ out,
    float* __restrict__ logdet)
{
    const int tid = threadIdx.x;
    const int m = blockIdx.x*256 + tid;
    float p[32];
    #pragma unroll
    for(int j=0;j<8;++j) ((float4*)p)[j] = ((const float4*)P)[(size_t)m*8+j];
    const float x0 = x[(size_t)m*2];
    const float x1 = x[(size_t)m*2+1];
    const float mk = mask[m];
    const float sc = 0.0625f;

    float cw[11], ch_[11], d[11];
    {
        float mx=-1e30f;
        #pragma unroll
        for(int j=0;j<10;++j) mx = fmaxf(mx, p[j]);
        float e[10]; float se=0.f;
        #pragma unroll
        for(int j=0;j<10;++j){ e[j]=__expf((p[j]-mx)*sc); se+=e[j]; }
        const float inv = __builtin_amdgcn_rcpf(se);
        float cum=0.f;
        cw[0]=-TBF;
        #pragma unroll
        for(int j=0;j<10;++j){ cum += fmaf(0.99f, e[j]*inv, 0.001f); cw[j+1]=fmaf(2.0f*TBF,cum,-TBF); }
        cw[10]=TBF;
    }
    {
        float mx=-1e30f;
        #pragma unroll
        for(int j=0;j<10;++j) mx = fmaxf(mx, p[10+j]);
        float e[10]; float se=0.f;
        #pragma unroll
        for(int j=0;j<10;++j){ e[j]=__expf((p[10+j]-mx)*sc); se+=e[j]; }
        const float inv = __builtin_amdgcn_rcpf(se);
        float cum=0.f;
        ch_[0]=-TBF;
        #pragma unroll
        for(int j=0;j<10;++j){ cum += fmaf(0.99f, e[j]*inv, 0.001f); ch_[j+1]=fmaf(2.0f*TBF,cum,-TBF); }
        ch_[10]=TBF;
    }
    d[0]=1.0f; d[10]=1.0f;
    #pragma unroll
    for(int k=1;k<10;++k) d[k] = 0.001f + softplusf_(p[19+k]);

    const bool inside = (x1>=-TBF)&&(x1<=TBF);
    const float xc = fminf(fmaxf(x1,-TBF),TBF);

    float icw=cw[0], ibw=cw[1]-cw[0], ich=ch_[0], ibh=ch_[1]-ch_[0], dk=d[0], dk1=d[1];
    #pragma unroll
    for(int j=1;j<10;++j){
        const bool sel = (xc>=cw[j]);
        icw = sel? cw[j]        : icw;
        ibw = sel? cw[j+1]-cw[j]: ibw;
        ich = sel? ch_[j]       : ich;
        ibh = sel? ch_[j+1]-ch_[j]: ibh;
        dk  = sel? d[j]         : dk;
        dk1 = sel? d[j+1]       : dk1;
    }

    const float delta = __fdividef(ibh, ibw);
    const float th = __fdividef(xc-icw, ibw);
    const float th1m = th*(1.0f-th);
    const float denom = fmaf(fmaf(-2.0f,delta,dk+dk1), th1m, delta);
    const float num = ibh*fmaf(delta*th, th, dk*th1m);
    const float rcd = __builtin_amdgcn_rcpf(denom);
    const float yv = ich + num*rcd;
    const float omt = 1.0f-th;
    const float dnum = delta*delta*(dk1*th*th + 2.0f*delta*th1m + dk*omt*omt);
    const float lad = __logf(dnum*rcd*rcd);
    const float y1 = inside? yv : x1;
    const float lv = inside? lad : 0.0f;

    out[(size_t)m*2]   = x0*mk;
    out[(size_t)m*2+1] = y1*mk;

    __shared__ float red[256];
    red[tid]=lv*mk;
    __syncthreads();
    #pragma unroll
    for(int s=128;s>0;s>>=1){ if(tid<s) red[tid]+=red[tid+s]; __syncthreads(); }
    if(tid==0) atomicAdd(&logdet[blockIdx.x>>5], red[0]);
}

extern "C" void kernel_launch(void* const* d_in, const int* in_sizes, int n_in,
                              void* d_out, int out_size, void* d_ws, size_t ws_size,
                              hipStream_t stream)
{
    const float* x      = (const float*)d_in[0];
    const float* mask   = (const float*)d_in[1];
    const float* w_pre  = (const float*)d_in[2];
    const float* b_pre  = (const float*)d_in[3];
    const float* dw_k   = (const float*)d_in[4];
    const float* dw_b   = (const float*)d_in[5];
    const float* w11    = (const float*)d_in[6];
    const float* b11    = (const float*)d_in[7];
    const float* ln1g   = (const float*)d_in[8];
    const float* ln1b   = (const float*)d_in[9];
    const float* ln2g   = (const float*)d_in[10];
    const float* ln2b   = (const float*)d_in[11];
    const float* w_proj = (const float*)d_in[12];
    const float* b_proj = (const float*)d_in[13];

    const size_t hbytes_bf16 = (size_t)MM*FF*2;        // 64 MiB each
    __hip_bfloat16* h0 = (__hip_bfloat16*)d_ws;
    __hip_bfloat16* h1 = h0 + (size_t)MM*FF;
    float* outp   = (float*)d_out;
    float* logdet = outp + (size_t)MM*2;

    const size_t wimg_bytes = (size_t)3*163840 + 20480;
    __hip_bfloat16* wimg;
    const bool ws_ok = (ws_size >= 2*hbytes_bf16 + wimg_bytes);
    if(ws_ok) wimg = (__hip_bfloat16*)((char*)d_ws + 2*hbytes_bf16);
    else      wimg = (__hip_bfloat16*)d_out;
    __hip_bfloat16* wpimg = wimg + (size_t)3*81920;

    wprep_kernel<<<32, 256, 0, stream>>>(w11, w_proj, wimg, wpimg);

    layer_kernel<<<MM/32, 256, 0, stream>>>(
        (const __hip_bfloat16*)nullptr, h1, x, w_pre, b_pre, mask,
        dw_k, dw_b, ln1g, ln1b, wimg, b11, ln2g, ln2b, 1, 1);
    layer_kernel<<<MM/32, 256, 0, stream>>>(
        h1, h0, x, w_pre, b_pre, mask,
        dw_k + (size_t)3*FF, dw_b + (size_t)FF,
        ln1g + (size_t)FF, ln1b + (size_t)FF,
        wimg + (size_t)81920, b11 + (size_t)FF,
        ln2g + (size_t)FF, ln2b + (size_t)FF, 3, 0);
    layer_kernel<<<MM/32, 256, 0, stream>>>(
        h0, h1, x, w_pre, b_pre, mask,
        dw_k + (size_t)6*FF, dw_b + (size_t)2*FF,
        ln1g + (size_t)2*FF, ln1b + (size_t)2*FF,
        wimg + (size_t)2*81920, b11 + (size_t)2*FF,
        ln2g + (size_t)2*FF, ln2b + (size_t)2*FF, 9, 0);

    hipMemsetAsync(logdet, 0, BB*sizeof(float), stream);
    if(ws_ok){
        projspline_kernel<<<MM/128, 256, 0, stream>>>(h1, mask, wpimg, b_proj, x, outp, logdet);
    } else {
        float* P = (float*)d_ws;
        proj_kernel<<<MM/64, 256, 0, stream>>>(h1, mask, wpimg, b_proj, P);
        spline_kernel<<<MM/256, 256, 0, stream>>>(P, x, mask, outp, logdet);
    }
}